// Round 21
// baseline (95.657 us; speedup 1.0000x reference)
//
#include <hip/hip_runtime.h>

#define SEG 24
#define DD  32
#define HEPS 1e-7f
#define N_ITERS 10
#define IPB 64                         // items per chunk
#define NCH 2                          // chunks per block (software pipeline)

typedef _Float16 h2    __attribute__((ext_vector_type(2)));
typedef _Float16 half8 __attribute__((ext_vector_type(8)));
typedef float    f32x4 __attribute__((ext_vector_type(4)));

__device__ __forceinline__ float frcp(float x) { return __builtin_amdgcn_rcpf(x); }

__device__ __forceinline__ float qx1(float x) {
    return __int_as_float(__builtin_amdgcn_mov_dpp(__float_as_int(x), 0xB1, 0xF, 0xF, true));
}
__device__ __forceinline__ float qx2(float x) {
    return __int_as_float(__builtin_amdgcn_mov_dpp(__float_as_int(x), 0x4E, 0xF, 0xF, true));
}
__device__ __forceinline__ float qsum(float x) {
    x += qx1(x);
    x += qx2(x);
    return x;
}

__device__ __forceinline__ float acosh_coef(float a) {
    float am = fmaf(a, a, -1.0f);
    float s  = sqrtf(am);
    return __logf(a + s) * frcp(s);
}

__device__ __forceinline__ float edot8(const float a[8], const float b[8]) {
    float x = fmaf(a[0], b[0], a[1] * b[1]);
    float y = fmaf(a[2], b[2], a[3] * b[3]);
    float z = fmaf(a[4], b[4], a[5] * b[5]);
    float w = fmaf(a[6], b[6], a[7] * b[7]);
    return qsum((x + y) + (z + w));
}

// round-to-nearest-even f16 packing
__device__ __forceinline__ unsigned pk_rne_u32(float a, float b) {
    union { _Float16 h[2]; unsigned u; } c;
    c.h[0] = (_Float16)a;
    c.h[1] = (_Float16)b;
    return c.u;
}
__device__ __forceinline__ h2 pk_rne_h2(float a, float b) {
    h2 r;
    r[0] = (_Float16)a;
    r[1] = (_Float16)b;
    return r;
}

// nontemporal 16B store via clang ext-vector
__device__ __forceinline__ void nt_store4(float* p, float4 v) {
    f32x4 w = { v.x, v.y, v.z, v.w };
    __builtin_nontemporal_store(w, reinterpret_cast<f32x4*>(p));
}

// ws layout (dwords):
//   [0,2048)    B-fragments f16x2, ts-folded:  idx = ((s*2+nt)*64 + lane)*4 + q
//   [2048,2176) b' = b*ts  f32  (s*32 + d)
//   [2176,2180) softmax(lorentz_weights) f32
#define WS_BP_OFF 2048
#define WS_W_OFF  2176

// ============ K0: pack B fragments (W^T*ts), b*ts, softmax(lw) -> d_ws ======
__global__ __launch_bounds__(256)
void prep_kernel(const float* __restrict__ W0, const float* __restrict__ b0,
                 const float* __restrict__ W1, const float* __restrict__ b1,
                 const float* __restrict__ W2, const float* __restrict__ b2,
                 const float* __restrict__ W3, const float* __restrict__ b3,
                 const float* __restrict__ es, const float* __restrict__ lw,
                 unsigned* __restrict__ ws)
{
    const int t = blockIdx.x * blockDim.x + threadIdx.x;
    const float* Ws[4] = { W0, W1, W2, W3 };
    const float* bs[4] = { b0, b1, b2, b3 };
    const float ts = tanhf(es[0]);
    if (t < 2048) {
        int s    = t >> 9;
        int rem  = t & 511;
        int nt   = rem >> 8;
        int lane = (rem >> 2) & 63;
        int q    = rem & 3;
        int n    = nt * 16 + (lane & 15);
        int k0   = (lane >> 4) * 8 + 2 * q;
        const float* W = Ws[s];
        float a = (k0     < SEG) ? W[n * SEG + k0]     * ts : 0.0f;
        float c = (k0 + 1 < SEG) ? W[n * SEG + k0 + 1] * ts : 0.0f;
        ws[t] = pk_rne_u32(a, c);
    } else if (t < 2176) {
        int p = t - 2048;
        reinterpret_cast<float*>(ws)[WS_BP_OFF + p] = bs[p / 32][p % 32] * ts;
    } else if (t == 2176) {
        float l0 = lw[0], l1 = lw[1], l2 = lw[2], l3 = lw[3];
        float mxw = fmaxf(fmaxf(l0, l1), fmaxf(l2, l3));
        float e0 = __expf(l0 - mxw), e1 = __expf(l1 - mxw),
              e2 = __expf(l2 - mxw), e3 = __expf(l3 - mxw);
        float winv = frcp(e0 + e1 + e2 + e3);
        float* wf = reinterpret_cast<float*>(ws);
        wf[WS_W_OFF + 0] = e0 * winv;
        wf[WS_W_OFF + 1] = e1 * winv;
        wf[WS_W_OFF + 2] = e2 * winv;
        wf[WS_W_OFF + 3] = e3 * winv;
    }
}

// ============ K1: fused; 2-chunk pipelined MFMA encode + 5-d Frechet ========
#define GMV(o0,o1,o2,o3,o4, v0,v1,v2,v3,v4)                                   \
    o0 = fmaf(G00,(v0), fmaf(G01,(v1), fmaf(G02,(v2), fmaf(G03,(v3), nt0*(v4))))); \
    o1 = fmaf(G01,(v0), fmaf(G11,(v1), fmaf(G12,(v2), fmaf(G13,(v3), nt1*(v4))))); \
    o2 = fmaf(G02,(v0), fmaf(G12,(v1), fmaf(G22,(v2), fmaf(G23,(v3), nt2*(v4))))); \
    o3 = fmaf(G03,(v0), fmaf(G13,(v1), fmaf(G23,(v2), fmaf(G33,(v3), nt3*(v4))))); \
    o4 = fmaf(nt0,(v0), fmaf(nt1,(v1), fmaf(nt2,(v2), fmaf(nt3,(v3), -(v4)))));

#define DOT5(a0,a1,a2,a3,a4, c0,c1,c2,c3,c4) \
    fmaf((a0),(c0), fmaf((a1),(c1), fmaf((a2),(c2), fmaf((a3),(c3), (a4)*(c4)))))

__global__ __launch_bounds__(256)
void fused_kernel(const float* __restrict__ x0, const float* __restrict__ x1,
                  const float* __restrict__ x2, const float* __restrict__ x3,
                  const unsigned* __restrict__ ws,
                  float* __restrict__ out, int n_items)
{
    __shared__ __align__(16) unsigned char smem[4 * IPB * 8 * 16];   // 32 KB
    float4* lds4 = reinterpret_cast<float4*>(smem);
    float*  ldsf = reinterpret_cast<float*>(smem);
    float (*gstate)[20] = reinterpret_cast<float (*)[20]>(smem);
    float (*betas)[5]   = reinterpret_cast<float (*)[5]>(smem + IPB * 20 * 4);

    const int tid = threadIdx.x;
    const size_t osz = (size_t)n_items * DD;
    const float* wsf = reinterpret_cast<const float*>(ws);

    // ---- hoisted, chunk-invariant state ----
    const int w    = tid >> 6;                       // wave id = stream id
    const int lane = tid & 63;
    const int g    = lane >> 4;
    const int lm   = lane & 15;
    const int s1   = w;                              // phase-1b stream
    const int il1  = tid & 63;
    const int il2  = tid >> 2;
    const int sub  = tid & 3;

    const float* xp;
    if      (w == 0) xp = x0;
    else if (w == 1) xp = x1;
    else if (w == 2) xp = x2;
    else             xp = x3;

    union { uint4 u; half8 v; } Bf0, Bf1;
    Bf0.u = reinterpret_cast<const uint4*>(ws)[(w * 2 + 0) * 64 + lane];
    Bf1.u = reinterpret_cast<const uint4*>(ws)[(w * 2 + 1) * 64 + lane];
    const float bv0 = wsf[WS_BP_OFF + w * 32 + lm];
    const float bv1 = wsf[WS_BP_OFF + w * 32 + 16 + lm];
    const f32x4 init0 = { bv0, bv0, bv0, bv0 };
    const f32x4 init1 = { bv1, bv1, bv1, bv1 };

    // ---- prefetch chunk 0 x into registers ----
    float4 xa[8];
    {
        const int item0 = (blockIdx.x * NCH) * IPB;
        #pragma unroll
        for (int m = 0; m < 4; ++m) {
            int item = item0 + m * 16 + lm;
            if (g < 3 && item < n_items) {
                const float4* ap = reinterpret_cast<const float4*>(
                    xp + (size_t)item * SEG + g * 8);
                xa[2*m]   = ap[0];
                xa[2*m+1] = ap[1];
            }
        }
    }

    for (int c = 0; c < NCH; ++c) {
        const int item0 = (blockIdx.x * NCH + c) * IPB;

        // ---------------- phase 1: pack A from xa, prefetch next, MFMA -----
        {
            half8 Av[4];
            #pragma unroll
            for (int m = 0; m < 4; ++m) {
                union { h2 h[4]; half8 v; } A;
                A.h[0] = pk_rne_h2(0.f, 0.f); A.h[1] = pk_rne_h2(0.f, 0.f);
                A.h[2] = pk_rne_h2(0.f, 0.f); A.h[3] = pk_rne_h2(0.f, 0.f);
                int item = item0 + m * 16 + lm;
                if (g < 3 && item < n_items) {
                    float4 a0 = xa[2*m], a1 = xa[2*m+1];
                    A.h[0] = pk_rne_h2(a0.x, a0.y);
                    A.h[1] = pk_rne_h2(a0.z, a0.w);
                    A.h[2] = pk_rne_h2(a1.x, a1.y);
                    A.h[3] = pk_rne_h2(a1.z, a1.w);
                }
                Av[m] = A.v;
            }

            // issue next chunk's x loads (xa regs now dead) — they complete
            // under this chunk's remaining ~5k-cycle phase train
            if (c + 1 < NCH) {
                const int ni0 = item0 + IPB;
                #pragma unroll
                for (int m = 0; m < 4; ++m) {
                    int item = ni0 + m * 16 + lm;
                    if (g < 3 && item < n_items) {
                        const float4* ap = reinterpret_cast<const float4*>(
                            xp + (size_t)item * SEG + g * 8);
                        xa[2*m]   = ap[0];
                        xa[2*m+1] = ap[1];
                    }
                }
            }

            f32x4 acc[4][2];
            #pragma unroll
            for (int m = 0; m < 4; ++m) {
                acc[m][0] = __builtin_amdgcn_mfma_f32_16x16x32_f16(Av[m], Bf0.v, init0, 0, 0, 0);
                acc[m][1] = __builtin_amdgcn_mfma_f32_16x16x32_f16(Av[m], Bf1.v, init1, 0, 0, 0);
            }

            // scatter u = acc into the swizzled LDS h-layout
            #pragma unroll
            for (int r = 0; r < 4; ++r) {
                int i7   = (g * 4 + r) & 7;
                int it_b = w * IPB + g * 4 + r;      // + m*16 via m*512 floats
                int s0 = (it_b * 8 + ((lm >> 2)       ^ i7)) * 4 + (lm & 3);
                int s1x = (it_b * 8 + ((4 + (lm >> 2)) ^ i7)) * 4 + (lm & 3);
                #pragma unroll
                for (int m = 0; m < 4; ++m) {
                    ldsf[s0 + m * 512]  = acc[m][0][r];
                    ldsf[s1x + m * 512] = acc[m][1][r];
                }
            }
        }

        // ---------------- phase 1b: per-thread nonlinear (same wave) -------
        {
            const int it1 = item0 + il1;
            if (it1 < n_items) {
                float u[DD];
                #pragma unroll
                for (int j = 0; j < DD / 4; ++j) {
                    float4 v = lds4[(s1 * IPB + il1) * 8 + (j ^ (il1 & 7))];
                    u[4*j+0] = v.x; u[4*j+1] = v.y; u[4*j+2] = v.z; u[4*j+3] = v.w;
                }

                float q0 = 0.f, q1 = 0.f, q2 = 0.f, q3 = 0.f;
                #pragma unroll
                for (int d = 0; d < DD; d += 4) {
                    q0 = fmaf(u[d+0], u[d+0], q0);
                    q1 = fmaf(u[d+1], u[d+1], q1);
                    q2 = fmaf(u[d+2], u[d+2], q2);
                    q3 = fmaf(u[d+3], u[d+3], q3);
                }
                float sq = (q0 + q1) + (q2 + q3) - 2.0f * u[0] * u[0];
                sq = fmaxf(sq, 1e-12f);
                float nrm = sqrtf(sq);
                float ep = __expf(nrm), em = frcp(ep);
                float sh = 0.5f * (ep - em);
                float sc = sh * frcp(fmaxf(nrm, HEPS));

                float r0 = 0.f, r1 = 0.f, r2 = 0.f, r3 = 0.f;
                #pragma unroll
                for (int d = 1; d < DD; ++d) {
                    float yv = sc * u[d];
                    u[d] = yv;
                    if ((d & 3) == 0) r0 = fmaf(yv, yv, r0);
                    else if ((d & 3) == 1) r1 = fmaf(yv, yv, r1);
                    else if ((d & 3) == 2) r2 = fmaf(yv, yv, r2);
                    else r3 = fmaf(yv, yv, r3);
                }
                u[0] = sqrtf(1.0f + (r0 + r1) + (r2 + r3));  // projx time comp

                #pragma unroll
                for (int j = 0; j < DD / 4; ++j) {
                    int slot = (s1 * IPB + il1) * 8 + (j ^ (il1 & 7));
                    lds4[slot] = make_float4(u[4*j+0], u[4*j+1], u[4*j+2], u[4*j+3]);
                }
            }
        }

        __syncthreads();                             // B1: lds4 h complete

        // ---------------- phase 1.5: cooperative dense h store (nt) --------
        #pragma unroll
        for (int cc = 0; cc < 8; ++cc) {
            int f   = cc * 256 + tid;
            int s   = f >> 9;
            int rem = f & 511;
            int it  = rem >> 3;
            int j   = rem & 7;
            if (item0 + it < n_items) {
                int slot = (s * IPB + it) * 8 + (j ^ (it & 7));
                nt_store4(out + (size_t)s * osz + (size_t)item0 * DD + (size_t)rem * 4,
                          lds4[slot]);
            }
        }

        // ---------------- phase 2a: quad-layout hv load + Gram -------------
        const int item = item0 + il2;
        const bool act = (item < n_items);

        float hv[4][8];
        float Ga1=0,Ga2=0,Ga3=0, Gb1=0,Gb2=0, Gc0=0;
        float tau0r=0, tau1r=0, tau2r=0, tau3r=0;

        if (act) {
            #pragma unroll
            for (int s = 0; s < 4; ++s) {
                float4 a = lds4[(s * IPB + il2) * 8 + ((2*sub)     ^ (il2 & 7))];
                float4 b = lds4[(s * IPB + il2) * 8 + ((2*sub + 1) ^ (il2 & 7))];
                hv[s][0] = a.x; hv[s][1] = a.y; hv[s][2] = a.z; hv[s][3] = a.w;
                hv[s][4] = b.x; hv[s][5] = b.y; hv[s][6] = b.z; hv[s][7] = b.w;
            }

            const float is0 = (sub == 0) ? 1.0f : 0.0f;
            tau0r = qsum(is0 * hv[0][0]);
            tau1r = qsum(is0 * hv[1][0]);
            tau2r = qsum(is0 * hv[2][0]);
            tau3r = qsum(is0 * hv[3][0]);

            float d01 = edot8(hv[0], hv[1]);
            float d02 = edot8(hv[0], hv[2]);
            float d03 = edot8(hv[0], hv[3]);
            float d12 = edot8(hv[1], hv[2]);
            float d13 = edot8(hv[1], hv[3]);
            float d23 = edot8(hv[2], hv[3]);

            Ga1 = fmaf(-2.0f*tau0r, tau1r, d01);
            Ga2 = fmaf(-2.0f*tau0r, tau2r, d02);
            Ga3 = fmaf(-2.0f*tau0r, tau3r, d03);
            Gb1 = fmaf(-2.0f*tau1r, tau2r, d12);
            Gb2 = fmaf(-2.0f*tau1r, tau3r, d13);
            Gc0 = fmaf(-2.0f*tau2r, tau3r, d23);
        }

        __syncthreads();            // B2: all lds4 reads done -> safe to alias

        if (act && sub == 0) {
            float4* g4 = reinterpret_cast<float4*>(gstate[il2]);
            g4[0] = make_float4(Ga1, Ga2, Ga3, Gb1);
            g4[1] = make_float4(Gb2, Gc0, tau0r, tau1r);
            g4[2] = make_float4(tau2r, tau3r, 0.0f, 0.0f);
        }

        __syncthreads();                             // B3: gstate visible

        // ---------------- phase 2b: 5-d Frechet, ONE lane per item ---------
        if (tid < IPB && (item0 + tid) < n_items) {
            const float w0 = wsf[WS_W_OFF + 0];
            const float w1 = wsf[WS_W_OFF + 1];
            const float w2 = wsf[WS_W_OFF + 2];
            const float w3 = wsf[WS_W_OFF + 3];

            const float4* g4 = reinterpret_cast<const float4*>(gstate[tid]);
            float4 ga = g4[0], gb = g4[1], gc = g4[2];
            const float G00 = -1.0f, G11 = -1.0f, G22 = -1.0f, G33 = -1.0f;
            float G01 = ga.x, G02 = ga.y, G03 = ga.z, G12 = ga.w;
            float G13 = gb.x, G23 = gb.y;
            float tau0 = gb.z, tau1 = gb.w, tau2 = gc.x, tau3 = gc.y;
            float nt0 = -tau0, nt1 = -tau1, nt2 = -tau2, nt3 = -tau3;

            float b0v, b1v, b2v, b3v, b4v, g0, g1, g2, g3, g4s;
            {
                float al0 = fmaxf(tau0, 1.0f + HEPS);
                float al1 = fmaxf(tau1, 1.0f + HEPS);
                float al2 = fmaxf(tau2, 1.0f + HEPS);
                float al3 = fmaxf(tau3, 1.0f + HEPS);
                float cc0 = w0 * acosh_coef(al0);
                float cc1 = w1 * acosh_coef(al1);
                float cc2 = w2 * acosh_coef(al2);
                float cc3 = w3 * acosh_coef(al3);
                b0v = cc0; b1v = cc1; b2v = cc2; b3v = cc3;
                b4v = -DOT5(cc0, cc1, cc2, cc3, 0.0f, al0, al1, al2, al3, 0.0f);

                GMV(g0, g1, g2, g3, g4s, b0v, b1v, b2v, b3v, b4v);
                float gq = DOT5(g0, g1, g2, g3, g4s, b0v, b1v, b2v, b3v, b4v);
                float sq = fmaxf(gq, 1e-12f);
                float nrm = sqrtf(sq);
                float ep = __expf(nrm), em = frcp(ep);
                float ch = 0.5f * (ep + em);
                float sc = 0.5f * (ep - em) * frcp(fmaxf(nrm, HEPS));
                b0v *= sc; b1v *= sc; b2v *= sc; b3v *= sc;
                b4v = fmaf(sc, b4v, ch);

                GMV(g0, g1, g2, g3, g4s, b0v, b1v, b2v, b3v, b4v);
                float xx = DOT5(g0, g1, g2, g3, g4s, b0v, b1v, b2v, b3v, b4v);
                float xt = DOT5(b0v, b1v, b2v, b3v, b4v, tau0, tau1, tau2, tau3, 1.0f);
                float tc = sqrtf(fmaf(xt, xt, 1.0f + xx));
                float dl = tc - xt;
                b4v += dl;
                g0 = fmaf(dl, nt0, g0); g1 = fmaf(dl, nt1, g1);
                g2 = fmaf(dl, nt2, g2); g3 = fmaf(dl, nt3, g3);
                g4s -= dl;
            }

            for (int it = 0; it < N_ITERS; ++it) {
                float al0 = fmaxf(-g0, 1.0f + HEPS);
                float al1 = fmaxf(-g1, 1.0f + HEPS);
                float al2 = fmaxf(-g2, 1.0f + HEPS);
                float al3 = fmaxf(-g3, 1.0f + HEPS);
                float cc0 = w0 * acosh_coef(al0);
                float cc1 = w1 * acosh_coef(al1);
                float cc2 = w2 * acosh_coef(al2);
                float cc3 = w3 * acosh_coef(al3);
                float S = DOT5(cc0, cc1, cc2, cc3, 0.0f, al0, al1, al2, al3, 0.0f);

                float gm0 = fmaf(-S, b0v, cc0);
                float gm1 = fmaf(-S, b1v, cc1);
                float gm2 = fmaf(-S, b2v, cc2);
                float gm3 = fmaf(-S, b3v, cc3);
                float gm4 = -S * b4v;

                float Gg0, Gg1, Gg2, Gg3, Gg4;
                GMV(Gg0, Gg1, Gg2, Gg3, Gg4, gm0, gm1, gm2, gm3, gm4);
                float qq = DOT5(Gg0, Gg1, Gg2, Gg3, Gg4, gm0, gm1, gm2, gm3, gm4);

                float sq = fmaxf(0.25f * qq, 1e-12f);
                float nrm = sqrtf(sq);
                float ep = __expf(nrm), em = frcp(ep);
                float ch = 0.5f * (ep + em);
                float sc = 0.25f * (ep - em) * frcp(fmaxf(nrm, HEPS));

                b0v = fmaf(ch, b0v, sc * gm0);
                b1v = fmaf(ch, b1v, sc * gm1);
                b2v = fmaf(ch, b2v, sc * gm2);
                b3v = fmaf(ch, b3v, sc * gm3);
                b4v = fmaf(ch, b4v, sc * gm4);
                g0  = fmaf(ch, g0, sc * Gg0);
                g1  = fmaf(ch, g1, sc * Gg1);
                g2  = fmaf(ch, g2, sc * Gg2);
                g3  = fmaf(ch, g3, sc * Gg3);
                g4s = fmaf(ch, g4s, sc * Gg4);

                float xx = DOT5(g0, g1, g2, g3, g4s, b0v, b1v, b2v, b3v, b4v);
                float xt = DOT5(b0v, b1v, b2v, b3v, b4v, tau0, tau1, tau2, tau3, 1.0f);
                float tc = sqrtf(fmaf(xt, xt, 1.0f + xx));
                float dl = tc - xt;
                b4v += dl;
                g0 = fmaf(dl, nt0, g0); g1 = fmaf(dl, nt1, g1);
                g2 = fmaf(dl, nt2, g2); g3 = fmaf(dl, nt3, g3);
                g4s -= dl;
            }

            betas[tid][0] = b0v;
            betas[tid][1] = b1v;
            betas[tid][2] = b2v;
            betas[tid][3] = b3v;
            betas[tid][4] = b4v;
        }

        __syncthreads();                             // B4: betas visible

        // ---------------- phase 2c: reconstruction (nt stores) -------------
        if (act) {
            float b0v = betas[il2][0];
            float b1v = betas[il2][1];
            float b2v = betas[il2][2];
            float b3v = betas[il2][3];
            float b4v = betas[il2][4];

            float r[8];
            #pragma unroll
            for (int j = 0; j < 8; ++j)
                r[j] = fmaf(b0v, hv[0][j], fmaf(b1v, hv[1][j],
                       fmaf(b2v, hv[2][j], b3v * hv[3][j])));
            if (sub == 0) r[0] += b4v;

            float* po = out + (size_t)4 * osz + (size_t)item * DD + sub * 8;
            nt_store4(po + 0, make_float4(r[0], r[1], r[2], r[3]));
            nt_store4(po + 4, make_float4(r[4], r[5], r[6], r[7]));
        }

        if (c + 1 < NCH)
            __syncthreads();                         // B5: protect LDS reuse
    }
}

extern "C" void kernel_launch(void* const* d_in, const int* in_sizes, int n_in,
                              void* d_out, int out_size, void* d_ws, size_t ws_size,
                              hipStream_t stream)
{
    const float* x0 = (const float*)d_in[0];
    const float* x1 = (const float*)d_in[1];
    const float* x2 = (const float*)d_in[2];
    const float* x3 = (const float*)d_in[3];
    const float* W0 = (const float*)d_in[4];
    const float* b0 = (const float*)d_in[5];
    const float* W1 = (const float*)d_in[6];
    const float* b1 = (const float*)d_in[7];
    const float* W2 = (const float*)d_in[8];
    const float* b2 = (const float*)d_in[9];
    const float* W3 = (const float*)d_in[10];
    const float* b3 = (const float*)d_in[11];
    const float* es = (const float*)d_in[12];
    const float* lw = (const float*)d_in[13];

    const int n_items = in_sizes[0] / SEG;   // 262144
    prep_kernel<<<9, 256, 0, stream>>>(W0, b0, W1, b1, W2, b2, W3, b3,
                                       es, lw, (unsigned*)d_ws);

    const int gx = (n_items + IPB * NCH - 1) / (IPB * NCH);   // 2048
    fused_kernel<<<gx, 256, 0, stream>>>(x0, x1, x2, x3,
                                         (const unsigned*)d_ws,
                                         (float*)d_out, n_items);
}

// Round 22
// 69.367 us; speedup vs baseline: 1.3790x; 1.3790x over previous
//
#include <hip/hip_runtime.h>

#define SEG 24
#define DD  32
#define HEPS 1e-7f
#define N_ITERS 10
#define IPB 64                         // items per block

typedef _Float16 h2    __attribute__((ext_vector_type(2)));
typedef _Float16 half8 __attribute__((ext_vector_type(8)));
typedef float    f32x4 __attribute__((ext_vector_type(4)));

__device__ __forceinline__ float frcp(float x) { return __builtin_amdgcn_rcpf(x); }

__device__ __forceinline__ float qx1(float x) {
    return __int_as_float(__builtin_amdgcn_mov_dpp(__float_as_int(x), 0xB1, 0xF, 0xF, true));
}
__device__ __forceinline__ float qx2(float x) {
    return __int_as_float(__builtin_amdgcn_mov_dpp(__float_as_int(x), 0x4E, 0xF, 0xF, true));
}
__device__ __forceinline__ float qsum(float x) {
    x += qx1(x);
    x += qx2(x);
    return x;
}

__device__ __forceinline__ float acosh_coef(float a) {
    float am = fmaf(a, a, -1.0f);
    float s  = sqrtf(am);
    return __logf(a + s) * frcp(s);
}

__device__ __forceinline__ float edot8(const float a[8], const float b[8]) {
    float x = fmaf(a[0], b[0], a[1] * b[1]);
    float y = fmaf(a[2], b[2], a[3] * b[3]);
    float z = fmaf(a[4], b[4], a[5] * b[5]);
    float w = fmaf(a[6], b[6], a[7] * b[7]);
    return qsum((x + y) + (z + w));
}

// round-to-nearest-even f16 packing
__device__ __forceinline__ unsigned pk_rne_u32(float a, float b) {
    union { _Float16 h[2]; unsigned u; } c;
    c.h[0] = (_Float16)a;
    c.h[1] = (_Float16)b;
    return c.u;
}
__device__ __forceinline__ h2 pk_rne_h2(float a, float b) {
    h2 r;
    r[0] = (_Float16)a;
    r[1] = (_Float16)b;
    return r;
}

// nontemporal 16B store via clang ext-vector (HIP float4 struct is rejected)
__device__ __forceinline__ void nt_store4(float* p, float4 v) {
    f32x4 w = { v.x, v.y, v.z, v.w };
    __builtin_nontemporal_store(w, reinterpret_cast<f32x4*>(p));
}

// ws layout (dwords):
//   [0,2048)    B-fragments f16x2, ts-folded:  idx = ((s*2+nt)*64 + lane)*4 + q
//   [2048,2176) b' = b*ts  f32  (s*32 + d)
//   [2176,2180) softmax(lorentz_weights) f32
#define WS_BP_OFF 2048
#define WS_W_OFF  2176

// ============ K0: pack B fragments (W^T*ts), b*ts, softmax(lw) -> d_ws ======
__global__ __launch_bounds__(256)
void prep_kernel(const float* __restrict__ W0, const float* __restrict__ b0,
                 const float* __restrict__ W1, const float* __restrict__ b1,
                 const float* __restrict__ W2, const float* __restrict__ b2,
                 const float* __restrict__ W3, const float* __restrict__ b3,
                 const float* __restrict__ es, const float* __restrict__ lw,
                 unsigned* __restrict__ ws)
{
    const int t = blockIdx.x * blockDim.x + threadIdx.x;
    const float* Ws[4] = { W0, W1, W2, W3 };
    const float* bs[4] = { b0, b1, b2, b3 };
    const float ts = tanhf(es[0]);
    if (t < 2048) {
        int s    = t >> 9;
        int rem  = t & 511;
        int nt   = rem >> 8;
        int lane = (rem >> 2) & 63;
        int q    = rem & 3;
        int n    = nt * 16 + (lane & 15);
        int k0   = (lane >> 4) * 8 + 2 * q;
        const float* W = Ws[s];
        float a = (k0     < SEG) ? W[n * SEG + k0]     * ts : 0.0f;
        float c = (k0 + 1 < SEG) ? W[n * SEG + k0 + 1] * ts : 0.0f;
        ws[t] = pk_rne_u32(a, c);
    } else if (t < 2176) {
        int p = t - 2048;
        reinterpret_cast<float*>(ws)[WS_BP_OFF + p] = bs[p / 32][p % 32] * ts;
    } else if (t == 2176) {
        float l0 = lw[0], l1 = lw[1], l2 = lw[2], l3 = lw[3];
        float mxw = fmaxf(fmaxf(l0, l1), fmaxf(l2, l3));
        float e0 = __expf(l0 - mxw), e1 = __expf(l1 - mxw),
              e2 = __expf(l2 - mxw), e3 = __expf(l3 - mxw);
        float winv = frcp(e0 + e1 + e2 + e3);
        float* wf = reinterpret_cast<float*>(ws);
        wf[WS_W_OFF + 0] = e0 * winv;
        wf[WS_W_OFF + 1] = e1 * winv;
        wf[WS_W_OFF + 2] = e2 * winv;
        wf[WS_W_OFF + 3] = e3 * winv;
    }
}

// ============ K1: fused; MFMA encode + LDS hand-off + 5-d Frechet ===========
#define GMV(o0,o1,o2,o3,o4, v0,v1,v2,v3,v4)                                   \
    o0 = fmaf(G00,(v0), fmaf(G01,(v1), fmaf(G02,(v2), fmaf(G03,(v3), nt0*(v4))))); \
    o1 = fmaf(G01,(v0), fmaf(G11,(v1), fmaf(G12,(v2), fmaf(G13,(v3), nt1*(v4))))); \
    o2 = fmaf(G02,(v0), fmaf(G12,(v1), fmaf(G22,(v2), fmaf(G23,(v3), nt2*(v4))))); \
    o3 = fmaf(G03,(v0), fmaf(G13,(v1), fmaf(G23,(v2), fmaf(G33,(v3), nt3*(v4))))); \
    o4 = fmaf(nt0,(v0), fmaf(nt1,(v1), fmaf(nt2,(v2), fmaf(nt3,(v3), -(v4)))));

#define DOT5(a0,a1,a2,a3,a4, c0,c1,c2,c3,c4) \
    fmaf((a0),(c0), fmaf((a1),(c1), fmaf((a2),(c2), fmaf((a3),(c3), (a4)*(c4)))))

__global__ __launch_bounds__(256)
void fused_kernel(const float* __restrict__ x0, const float* __restrict__ x1,
                  const float* __restrict__ x2, const float* __restrict__ x3,
                  const unsigned* __restrict__ ws,
                  float* __restrict__ out, int n_items)
{
    __shared__ __align__(16) unsigned char smem[4 * IPB * 8 * 16];   // 32 KB
    float4* lds4 = reinterpret_cast<float4*>(smem);
    float*  ldsf = reinterpret_cast<float*>(smem);
    float (*gstate)[20] = reinterpret_cast<float (*)[20]>(smem);
    float (*betas)[5]   = reinterpret_cast<float (*)[5]>(smem + IPB * 20 * 4);

    const int tid   = threadIdx.x;
    const int item0 = blockIdx.x * IPB;
    const size_t osz = (size_t)n_items * DD;

    const float* wsf = reinterpret_cast<const float*>(ws);

    // ---------------- phase 1: MFMA encode, one stream per wave ------------
    {
        const int w    = tid >> 6;                   // wave id = stream id
        const int lane = tid & 63;
        const int g    = lane >> 4;
        const int lm   = lane & 15;

        const float* xp;
        if      (w == 0) xp = x0;
        else if (w == 1) xp = x1;
        else if (w == 2) xp = x2;
        else             xp = x3;

        union { uint4 u; half8 v; } Bf0, Bf1;
        Bf0.u = reinterpret_cast<const uint4*>(ws)[(w * 2 + 0) * 64 + lane];
        Bf1.u = reinterpret_cast<const uint4*>(ws)[(w * 2 + 1) * 64 + lane];
        const float bv0 = wsf[WS_BP_OFF + w * 32 + lm];
        const float bv1 = wsf[WS_BP_OFF + w * 32 + 16 + lm];
        const f32x4 init0 = { bv0, bv0, bv0, bv0 };
        const f32x4 init1 = { bv1, bv1, bv1, bv1 };

        f32x4 acc[4][2];
        #pragma unroll
        for (int m = 0; m < 4; ++m) {
            union { h2 h[4]; half8 v; } A;
            A.h[0] = pk_rne_h2(0.f, 0.f); A.h[1] = pk_rne_h2(0.f, 0.f);
            A.h[2] = pk_rne_h2(0.f, 0.f); A.h[3] = pk_rne_h2(0.f, 0.f);
            int item = item0 + m * 16 + lm;
            if (g < 3 && item < n_items) {
                const float4* ap = reinterpret_cast<const float4*>(
                    xp + (size_t)item * SEG + g * 8);
                float4 a0 = ap[0], a1 = ap[1];
                A.h[0] = pk_rne_h2(a0.x, a0.y);
                A.h[1] = pk_rne_h2(a0.z, a0.w);
                A.h[2] = pk_rne_h2(a1.x, a1.y);
                A.h[3] = pk_rne_h2(a1.z, a1.w);
            }
            acc[m][0] = __builtin_amdgcn_mfma_f32_16x16x32_f16(A.v, Bf0.v, init0, 0, 0, 0);
            acc[m][1] = __builtin_amdgcn_mfma_f32_16x16x32_f16(A.v, Bf1.v, init1, 0, 0, 0);
        }

        // scatter u = acc into the swizzled LDS h-layout
        #pragma unroll
        for (int r = 0; r < 4; ++r) {
            int i7   = (g * 4 + r) & 7;
            int it_b = w * IPB + g * 4 + r;          // + m*16 via m*512 floats
            int s0 = (it_b * 8 + ((lm >> 2)       ^ i7)) * 4 + (lm & 3);
            int s1 = (it_b * 8 + ((4 + (lm >> 2)) ^ i7)) * 4 + (lm & 3);
            #pragma unroll
            for (int m = 0; m < 4; ++m) {
                ldsf[s0 + m * 512] = acc[m][0][r];
                ldsf[s1 + m * 512] = acc[m][1][r];
            }
        }
    }

    // ---------------- phase 1b: per-thread nonlinear (same wave) -----------
    {
        const int s1  = tid >> 6;
        const int il1 = tid & 63;
        const int it1 = item0 + il1;

        if (it1 < n_items) {
            float u[DD];
            #pragma unroll
            for (int j = 0; j < DD / 4; ++j) {
                float4 v = lds4[(s1 * IPB + il1) * 8 + (j ^ (il1 & 7))];
                u[4*j+0] = v.x; u[4*j+1] = v.y; u[4*j+2] = v.z; u[4*j+3] = v.w;
            }

            float q0 = 0.f, q1 = 0.f, q2 = 0.f, q3 = 0.f;
            #pragma unroll
            for (int d = 0; d < DD; d += 4) {
                q0 = fmaf(u[d+0], u[d+0], q0);
                q1 = fmaf(u[d+1], u[d+1], q1);
                q2 = fmaf(u[d+2], u[d+2], q2);
                q3 = fmaf(u[d+3], u[d+3], q3);
            }
            float sq = (q0 + q1) + (q2 + q3) - 2.0f * u[0] * u[0];
            sq = fmaxf(sq, 1e-12f);
            float nrm = sqrtf(sq);
            float ep = __expf(nrm), em = frcp(ep);
            float sh = 0.5f * (ep - em);
            float sc = sh * frcp(fmaxf(nrm, HEPS));

            float r0 = 0.f, r1 = 0.f, r2 = 0.f, r3 = 0.f;
            #pragma unroll
            for (int d = 1; d < DD; ++d) {
                float yv = sc * u[d];
                u[d] = yv;
                if ((d & 3) == 0) r0 = fmaf(yv, yv, r0);
                else if ((d & 3) == 1) r1 = fmaf(yv, yv, r1);
                else if ((d & 3) == 2) r2 = fmaf(yv, yv, r2);
                else r3 = fmaf(yv, yv, r3);
            }
            u[0] = sqrtf(1.0f + (r0 + r1) + (r2 + r3));      // projx time comp

            #pragma unroll
            for (int j = 0; j < DD / 4; ++j) {
                int slot = (s1 * IPB + il1) * 8 + (j ^ (il1 & 7));
                lds4[slot] = make_float4(u[4*j+0], u[4*j+1], u[4*j+2], u[4*j+3]);
            }
        }
    }

    __syncthreads();                                 // B1: lds4 h complete

    // ---------------- phase 1.5: cooperative dense h store (nontemporal) ---
    #pragma unroll
    for (int c = 0; c < 8; ++c) {
        int f   = c * 256 + tid;
        int s   = f >> 9;
        int rem = f & 511;
        int it  = rem >> 3;
        int j   = rem & 7;
        if (item0 + it < n_items) {
            int slot = (s * IPB + it) * 8 + (j ^ (it & 7));
            nt_store4(out + (size_t)s * osz + (size_t)item0 * DD + (size_t)rem * 4,
                      lds4[slot]);
        }
    }

    // ---------------- phase 2a: quad-layout hv load + Gram (to registers) --
    const int il2  = tid >> 2;
    const int sub  = tid & 3;
    const int item = item0 + il2;
    const bool act = (item < n_items);

    float hv[4][8];
    float Ga1=0,Ga2=0,Ga3=0, Gb1=0,Gb2=0, Gc0=0;
    float tau0r=0, tau1r=0, tau2r=0, tau3r=0;

    if (act) {
        #pragma unroll
        for (int s = 0; s < 4; ++s) {
            float4 a = lds4[(s * IPB + il2) * 8 + ((2*sub)     ^ (il2 & 7))];
            float4 b = lds4[(s * IPB + il2) * 8 + ((2*sub + 1) ^ (il2 & 7))];
            hv[s][0] = a.x; hv[s][1] = a.y; hv[s][2] = a.z; hv[s][3] = a.w;
            hv[s][4] = b.x; hv[s][5] = b.y; hv[s][6] = b.z; hv[s][7] = b.w;
        }

        const float is0 = (sub == 0) ? 1.0f : 0.0f;
        tau0r = qsum(is0 * hv[0][0]);
        tau1r = qsum(is0 * hv[1][0]);
        tau2r = qsum(is0 * hv[2][0]);
        tau3r = qsum(is0 * hv[3][0]);

        float d01 = edot8(hv[0], hv[1]);
        float d02 = edot8(hv[0], hv[2]);
        float d03 = edot8(hv[0], hv[3]);
        float d12 = edot8(hv[1], hv[2]);
        float d13 = edot8(hv[1], hv[3]);
        float d23 = edot8(hv[2], hv[3]);

        Ga1 = fmaf(-2.0f*tau0r, tau1r, d01);
        Ga2 = fmaf(-2.0f*tau0r, tau2r, d02);
        Ga3 = fmaf(-2.0f*tau0r, tau3r, d03);
        Gb1 = fmaf(-2.0f*tau1r, tau2r, d12);
        Gb2 = fmaf(-2.0f*tau1r, tau3r, d13);
        Gc0 = fmaf(-2.0f*tau2r, tau3r, d23);
    }

    __syncthreads();                // B2: all lds4 reads done -> safe to alias

    if (act && sub == 0) {
        float4* g4 = reinterpret_cast<float4*>(gstate[il2]);
        g4[0] = make_float4(Ga1, Ga2, Ga3, Gb1);
        g4[1] = make_float4(Gb2, Gc0, tau0r, tau1r);
        g4[2] = make_float4(tau2r, tau3r, 0.0f, 0.0f);
    }

    __syncthreads();                                 // B3: gstate visible

    // ---------------- phase 2b: 5-d Frechet, ONE lane per item -------------
    if (tid < IPB && (item0 + tid) < n_items) {
        const float w0 = wsf[WS_W_OFF + 0];          // wave-uniform s_loads
        const float w1 = wsf[WS_W_OFF + 1];
        const float w2 = wsf[WS_W_OFF + 2];
        const float w3 = wsf[WS_W_OFF + 3];

        const float4* g4 = reinterpret_cast<const float4*>(gstate[tid]);
        float4 ga = g4[0], gb = g4[1], gc = g4[2];
        const float G00 = -1.0f, G11 = -1.0f, G22 = -1.0f, G33 = -1.0f;
        float G01 = ga.x, G02 = ga.y, G03 = ga.z, G12 = ga.w;
        float G13 = gb.x, G23 = gb.y;
        float tau0 = gb.z, tau1 = gb.w, tau2 = gc.x, tau3 = gc.y;
        float nt0 = -tau0, nt1 = -tau1, nt2 = -tau2, nt3 = -tau3;

        float b0v, b1v, b2v, b3v, b4v, g0, g1, g2, g3, g4s;
        {
            float al0 = fmaxf(tau0, 1.0f + HEPS);
            float al1 = fmaxf(tau1, 1.0f + HEPS);
            float al2 = fmaxf(tau2, 1.0f + HEPS);
            float al3 = fmaxf(tau3, 1.0f + HEPS);
            float cc0 = w0 * acosh_coef(al0);
            float cc1 = w1 * acosh_coef(al1);
            float cc2 = w2 * acosh_coef(al2);
            float cc3 = w3 * acosh_coef(al3);
            b0v = cc0; b1v = cc1; b2v = cc2; b3v = cc3;
            b4v = -DOT5(cc0, cc1, cc2, cc3, 0.0f, al0, al1, al2, al3, 0.0f);

            GMV(g0, g1, g2, g3, g4s, b0v, b1v, b2v, b3v, b4v);
            float gq = DOT5(g0, g1, g2, g3, g4s, b0v, b1v, b2v, b3v, b4v);
            float sq = fmaxf(gq, 1e-12f);
            float nrm = sqrtf(sq);
            float ep = __expf(nrm), em = frcp(ep);
            float ch = 0.5f * (ep + em);
            float sc = 0.5f * (ep - em) * frcp(fmaxf(nrm, HEPS));
            b0v *= sc; b1v *= sc; b2v *= sc; b3v *= sc;
            b4v = fmaf(sc, b4v, ch);

            GMV(g0, g1, g2, g3, g4s, b0v, b1v, b2v, b3v, b4v);
            float xx = DOT5(g0, g1, g2, g3, g4s, b0v, b1v, b2v, b3v, b4v);
            float xt = DOT5(b0v, b1v, b2v, b3v, b4v, tau0, tau1, tau2, tau3, 1.0f);
            float tc = sqrtf(fmaf(xt, xt, 1.0f + xx));
            float dl = tc - xt;
            b4v += dl;
            g0 = fmaf(dl, nt0, g0); g1 = fmaf(dl, nt1, g1);
            g2 = fmaf(dl, nt2, g2); g3 = fmaf(dl, nt3, g3);
            g4s -= dl;
        }

        for (int it = 0; it < N_ITERS; ++it) {
            float al0 = fmaxf(-g0, 1.0f + HEPS);
            float al1 = fmaxf(-g1, 1.0f + HEPS);
            float al2 = fmaxf(-g2, 1.0f + HEPS);
            float al3 = fmaxf(-g3, 1.0f + HEPS);
            float cc0 = w0 * acosh_coef(al0);
            float cc1 = w1 * acosh_coef(al1);
            float cc2 = w2 * acosh_coef(al2);
            float cc3 = w3 * acosh_coef(al3);
            float S = DOT5(cc0, cc1, cc2, cc3, 0.0f, al0, al1, al2, al3, 0.0f);

            float gm0 = fmaf(-S, b0v, cc0);
            float gm1 = fmaf(-S, b1v, cc1);
            float gm2 = fmaf(-S, b2v, cc2);
            float gm3 = fmaf(-S, b3v, cc3);
            float gm4 = -S * b4v;

            float Gg0, Gg1, Gg2, Gg3, Gg4;
            GMV(Gg0, Gg1, Gg2, Gg3, Gg4, gm0, gm1, gm2, gm3, gm4);
            float qq = DOT5(Gg0, Gg1, Gg2, Gg3, Gg4, gm0, gm1, gm2, gm3, gm4);

            float sq = fmaxf(0.25f * qq, 1e-12f);
            float nrm = sqrtf(sq);
            float ep = __expf(nrm), em = frcp(ep);
            float ch = 0.5f * (ep + em);
            float sc = 0.25f * (ep - em) * frcp(fmaxf(nrm, HEPS));

            b0v = fmaf(ch, b0v, sc * gm0);
            b1v = fmaf(ch, b1v, sc * gm1);
            b2v = fmaf(ch, b2v, sc * gm2);
            b3v = fmaf(ch, b3v, sc * gm3);
            b4v = fmaf(ch, b4v, sc * gm4);
            g0  = fmaf(ch, g0, sc * Gg0);
            g1  = fmaf(ch, g1, sc * Gg1);
            g2  = fmaf(ch, g2, sc * Gg2);
            g3  = fmaf(ch, g3, sc * Gg3);
            g4s = fmaf(ch, g4s, sc * Gg4);

            float xx = DOT5(g0, g1, g2, g3, g4s, b0v, b1v, b2v, b3v, b4v);
            float xt = DOT5(b0v, b1v, b2v, b3v, b4v, tau0, tau1, tau2, tau3, 1.0f);
            float tc = sqrtf(fmaf(xt, xt, 1.0f + xx));
            float dl = tc - xt;
            b4v += dl;
            g0 = fmaf(dl, nt0, g0); g1 = fmaf(dl, nt1, g1);
            g2 = fmaf(dl, nt2, g2); g3 = fmaf(dl, nt3, g3);
            g4s -= dl;
        }

        betas[tid][0] = b0v;
        betas[tid][1] = b1v;
        betas[tid][2] = b2v;
        betas[tid][3] = b3v;
        betas[tid][4] = b4v;
    }

    __syncthreads();                                 // B4: betas visible

    // ---------------- phase 2c: reconstruction (quad layout, nontemporal) --
    if (act) {
        float b0v = betas[il2][0];
        float b1v = betas[il2][1];
        float b2v = betas[il2][2];
        float b3v = betas[il2][3];
        float b4v = betas[il2][4];

        float r[8];
        #pragma unroll
        for (int j = 0; j < 8; ++j)
            r[j] = fmaf(b0v, hv[0][j], fmaf(b1v, hv[1][j],
                   fmaf(b2v, hv[2][j], b3v * hv[3][j])));
        if (sub == 0) r[0] += b4v;

        float* po = out + (size_t)4 * osz + (size_t)item * DD + sub * 8;
        nt_store4(po + 0, make_float4(r[0], r[1], r[2], r[3]));
        nt_store4(po + 4, make_float4(r[4], r[5], r[6], r[7]));
    }
}

extern "C" void kernel_launch(void* const* d_in, const int* in_sizes, int n_in,
                              void* d_out, int out_size, void* d_ws, size_t ws_size,
                              hipStream_t stream)
{
    const float* x0 = (const float*)d_in[0];
    const float* x1 = (const float*)d_in[1];
    const float* x2 = (const float*)d_in[2];
    const float* x3 = (const float*)d_in[3];
    const float* W0 = (const float*)d_in[4];
    const float* b0 = (const float*)d_in[5];
    const float* W1 = (const float*)d_in[6];
    const float* b1 = (const float*)d_in[7];
    const float* W2 = (const float*)d_in[8];
    const float* b2 = (const float*)d_in[9];
    const float* W3 = (const float*)d_in[10];
    const float* b3 = (const float*)d_in[11];
    const float* es = (const float*)d_in[12];
    const float* lw = (const float*)d_in[13];

    const int n_items = in_sizes[0] / SEG;   // 262144
    prep_kernel<<<9, 256, 0, stream>>>(W0, b0, W1, b1, W2, b2, W3, b3,
                                       es, lw, (unsigned*)d_ws);

    const int gx = (n_items + IPB - 1) / IPB;       // 4096
    fused_kernel<<<gx, 256, 0, stream>>>(x0, x1, x2, x3,
                                         (const unsigned*)d_ws,
                                         (float*)d_out, n_items);
}